// Round 3
// baseline (311.107 us; speedup 1.0000x reference)
//
#include <hip/hip_runtime.h>

#define NS 5      // symbols
#define NW 33     // subcarriers
#define NA 16     // antennas
#define SW 165    // NS*NW
#define T2S 99    // T2 elems per matrix: NW cols x 3 Hermitian rows
#define MPW 5     // matrices per wave (5*TPM = 55 of 64 lanes active)
#define GM 20     // matrices per block = MPW * (THREADS/64)
#define TPM 11    // threads per matrix
#define CPT 3     // columns per thread
#define THREADS 256

// R12: drop the x-staging LDS buffer. All 11 threads of a matrix read the SAME
// x[t][w] (they differ only in Fsub columns), so direct global loads are
// hardware-broadcast within each group and L1/L2/L3-resident (FETCH_SIZE shows
// the whole problem is L3-warm). LDS shrinks 35.3->24.8 KB -> 6 blocks/CU
// (24 waves/CU, was 16) and the per-wave staging lgkmcnt(0) drain disappears.
// Kept: wave-autonomy (R10), packed complex FMA (R11), 256 threads, LDS sFsub.
typedef float f2 __attribute__((ext_vector_type(2)));

// z += x * f (complex).  inst1: (zr,zi) += (xr,xi)*(fr,fr)
//                        inst2: (zr,zi) += (-xi,xr)*(fi,fi)
__device__ __forceinline__ void cmac(f2& z, f2 x, f2 f) {
    asm("v_pk_fma_f32 %0, %1, %2, %0 op_sel:[0,0,0] op_sel_hi:[1,0,1]"
        : "+v"(z) : "v"(x), "v"(f));
    asm("v_pk_fma_f32 %0, %1, %2, %0 op_sel:[1,1,0] op_sel_hi:[0,1,1] neg_lo:[1,0,0]"
        : "+v"(z) : "v"(x), "v"(f));
}

// z += conj(f) * P, P real broadcast pair Pp=(P,P): lo zr+=f.x*P, hi zi+=-f.y*P
__device__ __forceinline__ void cmacr(f2& z, f2 f, f2 Pp) {
    asm("v_pk_fma_f32 %0, %1, %2, %0 op_sel:[0,0,0] op_sel_hi:[1,1,1] neg_hi:[1,0,0]"
        : "+v"(z) : "v"(f), "v"(Pp));
}

// plain packed: z += a*b elementwise
__device__ __forceinline__ void pkfma(f2& z, f2 a, f2 b) {
    asm("v_pk_fma_f32 %0, %1, %2, %0 op_sel:[0,0,0] op_sel_hi:[1,1,1]"
        : "+v"(z) : "v"(a), "v"(b));
}

__global__ __launch_bounds__(THREADS, 6) void autocorr_kernel(
    const float* __restrict__ x_real, const float* __restrict__ x_imag,
    const float* __restrict__ Fsym_re, const float* __restrict__ Fsym_im,
    const float* __restrict__ Fsub_re, const float* __restrict__ Fsub_im,
    float* __restrict__ out, int NM, int write_complex)
{
    __shared__ f2 sFsym[NS * NS];     // [s][t]
    __shared__ f2 sFsub[NW * NW];     // [w][v] row-major (symmetric matrix)
    __shared__ f2 t2buf[GM * T2S];    // T2 col-major [v][p<3], per-matrix stride 99

    const int tid = threadIdx.x;

    // ---- stage F matrices into LDS (cooperative; the ONLY barrier) ----
    for (int i = tid; i < NW * NW; i += THREADS)
        sFsub[i] = (f2){Fsub_re[i], Fsub_im[i]};
    if (tid < NS * NS) sFsym[tid] = (f2){Fsym_re[tid], Fsym_im[tid]};
    __syncthreads();

    const int wave = tid >> 6;
    const int lane = tid & 63;
    const int Mw = blockIdx.x * GM + wave * MPW;       // this wave's first matrix

    const int g = lane / TPM;                 // 0..4 active, 5 for idle lanes
    const int j = lane - g * TPM;
    const bool act = (lane < MPW * TPM);      // 55 of 64 lanes compute
    const int gg = act ? g : 0;               // clamp for address formation
    const int M = Mw + gg;
    const int c0 = 3 * j;

    // Safe x base even for pad/tail lanes (results discarded, loads in-bounds).
    const int Ms = (M < NM) ? M : 0;
    const int n = Ms >> 4, a = Ms & 15;
    const float* __restrict__ xr = x_real + (n * NS * NA + a) * NW;  // +t*528+w
    const float* __restrict__ xi = x_imag + (n * NS * NA + a) * NW;

    // ---- Fused A+B: V[t][k] = sum_w x[t][w] * Fsub[w][c0+k] ----
    // x read directly from global: identical address across the 11 lanes of a
    // group (broadcast-coalesced), 5 distinct addresses per wave, L1/L3-warm.
    f2 V[NS][CPT];
#pragma unroll
    for (int t = 0; t < NS; ++t)
#pragma unroll
        for (int k = 0; k < CPT; ++k) V[t][k] = (f2){0.f, 0.f};
    if (act) {
#pragma unroll 3
        for (int w = 0; w < NW; ++w) {
            f2 xc[NS];
#pragma unroll
            for (int t = 0; t < NS; ++t)
                xc[t] = (f2){xr[t * (NA * NW) + w], xi[t * (NA * NW) + w]};
            f2 fv[CPT];
#pragma unroll
            for (int k = 0; k < CPT; ++k) fv[k] = sFsub[w * NW + c0 + k];
#pragma unroll
            for (int t = 0; t < NS; ++t)
#pragma unroll
                for (int k = 0; k < CPT; ++k)
                    cmac(V[t][k], xc[t], fv[k]);   // 2 pk_fma
        }
    }

    // ---- X = F_sym*V (thread-local); P = |X|^2; Stage D (Hermitian p<3) -> T2 ----
    f2 T2[3][CPT];
#pragma unroll
    for (int p = 0; p < 3; ++p)
#pragma unroll
        for (int k = 0; k < CPT; ++k) T2[p][k] = (f2){0.f, 0.f};
    if (act) {
#pragma unroll
        for (int s = 0; s < NS; ++s) {
            f2 X[CPT];
#pragma unroll
            for (int k = 0; k < CPT; ++k) X[k] = (f2){0.f, 0.f};
#pragma unroll
            for (int t = 0; t < NS; ++t) {
                f2 f = sFsym[s * NS + t];   // broadcast
#pragma unroll
                for (int k = 0; k < CPT; ++k)
                    cmac(X[k], f, V[t][k]);
            }
#pragma unroll
            for (int k = 0; k < CPT; ++k) {
                const float Pv = X[k].x * X[k].x + X[k].y * X[k].y;
                const f2 Pp = (f2){Pv, Pv};
#pragma unroll
                for (int p = 0; p < 3; ++p)
                    cmacr(T2[p][k], sFsym[s * NS + p], Pp);
            }
        }
        // T2 col-major transpose through wave-private LDS region.
        // Write pattern (9 f2 at offset 9j per lane) is bank-conflict-free.
        f2* const wb = &t2buf[(wave * MPW + gg) * T2S];
#pragma unroll
        for (int k = 0; k < CPT; ++k)
#pragma unroll
            for (int p = 0; p < 3; ++p)
                wb[(c0 + k) * 3 + p] = T2[p][k];
    }
    // Wave-sync: per-wave DS ops complete in order; wait for our ds_writes,
    // memory clobber keeps the dependent ds_reads below. No __syncthreads.
    asm volatile("s_waitcnt lgkmcnt(0)" ::: "memory");

    // ---- Stage E: Y[p][q] = sum_v T2[p][v]*conj(Fsub[q][v]), q = c0+k ----
    if (act) {
        const f2* bp = &t2buf[(wave * MPW + gg) * T2S];
        if (!write_complex) {
            // Real part only: Re(tc*conj(fw)) = tc.x*fw.x + tc.y*fw.y.
            f2 Ypk[3][CPT];
#pragma unroll
            for (int p = 0; p < 3; ++p)
#pragma unroll
                for (int k = 0; k < CPT; ++k) Ypk[p][k] = (f2){0.f, 0.f};
#pragma unroll 3
            for (int v = 0; v < NW; ++v) {
                f2 tc[3];
#pragma unroll
                for (int p = 0; p < 3; ++p) tc[p] = bp[v * 3 + p];   // group broadcast
                f2 fw[CPT];
#pragma unroll
                for (int k = 0; k < CPT; ++k) fw[k] = sFsub[(c0 + k) * NW + v];
#pragma unroll
                for (int p = 0; p < 3; ++p)
#pragma unroll
                    for (int k = 0; k < CPT; ++k)
                        pkfma(Ypk[p][k], tc[p], fw[k]);   // fold at the end
            }
            if (M < NM) {
                int obase = ((n * NS) * NA + a) * NW;
#pragma unroll
                for (int p = 0; p < 3; ++p) {
                    const int pp = (NS - p) % NS;   // 0,4,3
#pragma unroll
                    for (int k = 0; k < CPT; ++k) {
                        const int q = c0 + k;
                        const int qq = (NW - q) % NW;
                        const float Yr = Ypk[p][k].x + Ypk[p][k].y;
                        out[obase + p * (NA * NW) + q] = Yr;
                        out[obase + pp * (NA * NW) + qq] = Yr;
                    }
                }
            }
        } else {
            // Fallback: full complex output (not expected on this harness).
            f2 Y[3][CPT];
#pragma unroll
            for (int p = 0; p < 3; ++p)
#pragma unroll
                for (int k = 0; k < CPT; ++k) Y[p][k] = (f2){0.f, 0.f};
            for (int v = 0; v < NW; ++v) {
                f2 tc[3];
#pragma unroll
                for (int p = 0; p < 3; ++p) tc[p] = bp[v * 3 + p];
                f2 fw[CPT];
#pragma unroll
                for (int k = 0; k < CPT; ++k) fw[k] = sFsub[(c0 + k) * NW + v];
#pragma unroll
                for (int p = 0; p < 3; ++p)
#pragma unroll
                    for (int k = 0; k < CPT; ++k) {
                        Y[p][k].x = fmaf(tc[p].x, fw[k].x, Y[p][k].x);
                        Y[p][k].x = fmaf(tc[p].y, fw[k].y, Y[p][k].x);
                        Y[p][k].y = fmaf(tc[p].y, fw[k].x, Y[p][k].y);
                        Y[p][k].y = fmaf(-tc[p].x, fw[k].y, Y[p][k].y);
                    }
            }
            if (M < NM) {
#pragma unroll
                for (int p = 0; p < 3; ++p) {
                    const int pp = (NS - p) % NS;
#pragma unroll
                    for (int k = 0; k < CPT; ++k) {
                        const int q = c0 + k;
                        const int qq = (NW - q) % NW;
                        ((float2*)out)[((n * NS + p) * NA + a) * NW + q] =
                            make_float2(Y[p][k].x, Y[p][k].y);
                        ((float2*)out)[((n * NS + pp) * NA + a) * NW + qq] =
                            make_float2(Y[p][k].x, -Y[p][k].y);
                    }
                }
            }
        }
    }
}

extern "C" void kernel_launch(void* const* d_in, const int* in_sizes, int n_in,
                              void* d_out, int out_size, void* d_ws, size_t ws_size,
                              hipStream_t stream) {
    const float* x_real  = (const float*)d_in[0];
    const float* x_imag  = (const float*)d_in[1];
    const float* Fsym_re = (const float*)d_in[2];
    const float* Fsym_im = (const float*)d_in[3];
    const float* Fsub_re = (const float*)d_in[4];
    const float* Fsub_im = (const float*)d_in[5];

    const int NM = in_sizes[0] / SW;
    const long long n_cplx = (long long)in_sizes[0];
    const int write_complex = ((long long)out_size >= 2 * n_cplx) ? 1 : 0;

    const int blocks = (NM + GM - 1) / GM;

    autocorr_kernel<<<blocks, THREADS, 0, stream>>>(
        x_real, x_imag, Fsym_re, Fsym_im, Fsub_re, Fsub_im,
        (float*)d_out, NM, write_complex);
}

// Round 4
// 184.623 us; speedup vs baseline: 1.6851x; 1.6851x over previous
//
#include <hip/hip_runtime.h>

#define NS 5      // symbols
#define NW 33     // subcarriers
#define NA 16     // antennas
#define SW 165    // NS*NW
#define BUFS 99   // per-matrix LDS buffer (f2): holds x-chunk (<=85), then T2 (99)
#define CW0 17    // chunk0 w-columns
#define CH0 (CW0*NS)   // 85 f2 per matrix
#define CW1 16    // chunk1 w-columns
#define CH1 (CW1*NS)   // 80 f2 per matrix
#define MPW 5     // matrices per wave
#define GM 20     // matrices per block
#define TPM 11    // threads per matrix
#define CPT 3     // columns per thread
#define THREADS 256

// R13: LDS-coalesced staging restored (R12 lesson: direct-global x = 6x
// line over-fetch), but buffer shrunk 165->99 f2/matrix via two w-chunks
// double-buffered through registers (T14: issue loads early, ds_write late).
// LDS 35.3->24.2 KB -> 6 blocks/CU (24 waves, was 16). Chunk1 overwrites
// chunk0's region: safe per-wave in-order DS (same argument as T2 overwrite).
typedef float f2 __attribute__((ext_vector_type(2)));

// z += x * f (complex).  inst1: (zr,zi) += (xr,xi)*(fr,fr)
//                        inst2: (zr,zi) += (-xi,xr)*(fi,fi)
__device__ __forceinline__ void cmac(f2& z, f2 x, f2 f) {
    asm("v_pk_fma_f32 %0, %1, %2, %0 op_sel:[0,0,0] op_sel_hi:[1,0,1]"
        : "+v"(z) : "v"(x), "v"(f));
    asm("v_pk_fma_f32 %0, %1, %2, %0 op_sel:[1,1,0] op_sel_hi:[0,1,1] neg_lo:[1,0,0]"
        : "+v"(z) : "v"(x), "v"(f));
}

// z += conj(f) * P, P real pair Pp=(P,P): lo zr+=f.x*P, hi zi+=-f.y*P
__device__ __forceinline__ void cmacr(f2& z, f2 f, f2 Pp) {
    asm("v_pk_fma_f32 %0, %1, %2, %0 op_sel:[0,0,0] op_sel_hi:[1,1,1] neg_hi:[1,0,0]"
        : "+v"(z) : "v"(f), "v"(Pp));
}

// plain packed: z += a*b elementwise
__device__ __forceinline__ void pkfma(f2& z, f2 a, f2 b) {
    asm("v_pk_fma_f32 %0, %1, %2, %0 op_sel:[0,0,0] op_sel_hi:[1,1,1]"
        : "+v"(z) : "v"(a), "v"(b));
}

// Load one x-chunk into registers (issued early; latency hides under other work).
#define STAGE_LOAD(R, CW, CH, W0, NE)                                      \
    _Pragma("unroll")                                                      \
    for (int i = 0; i < 7; ++i) {                                          \
        const int e = lane + i * 64;                                       \
        f2 v = (f2){0.f, 0.f};                                             \
        if (e < (NE)) {                                                    \
            const int gq = e / (CH), rq = e - gq * (CH);                   \
            const int tq = rq / (CW), wq = rq - tq * (CW);                 \
            const int Mq = Mw + gq;                                        \
            if (Mq < NM) {                                                 \
                const int nq = Mq >> 4, aq = Mq & 15;                      \
                const int go = ((nq * NS + tq) * NA + aq) * NW + (W0) + wq;\
                v = (f2){x_real[go], x_imag[go]};                          \
            }                                                              \
        }                                                                  \
        R[i] = v;                                                          \
    }

// Write a register-staged chunk into the wave-private LDS region.
#define STAGE_WRITE(R, CW, CH, NE)                                         \
    _Pragma("unroll")                                                      \
    for (int i = 0; i < 7; ++i) {                                          \
        const int e = lane + i * 64;                                       \
        if (e < (NE)) {                                                    \
            const int gq = e / (CH), rq = e - gq * (CH);                   \
            const int tq = rq / (CW), wq = rq - tq * (CW);                 \
            wbuf[gq * BUFS + wq * NS + tq] = R[i];                         \
        }                                                                  \
    }

__global__ __launch_bounds__(THREADS, 6) void autocorr_kernel(
    const float* __restrict__ x_real, const float* __restrict__ x_imag,
    const float* __restrict__ Fsym_re, const float* __restrict__ Fsym_im,
    const float* __restrict__ Fsub_re, const float* __restrict__ Fsub_im,
    float* __restrict__ out, int NM, int write_complex)
{
    __shared__ f2 sFsym[NS * NS];     // [s][t]
    __shared__ f2 sFsub[NW * NW];     // [w][v] row-major (symmetric)
    __shared__ f2 buf[GM * BUFS];     // per-matrix 99: x chunk, then T2 col-major

    const int tid = threadIdx.x;
    const int wave = tid >> 6;
    const int lane = tid & 63;
    const int Mw = blockIdx.x * GM + wave * MPW;
    f2* const wbuf = &buf[wave * MPW * BUFS];

    // ---- F staging (cooperative) ----
    for (int i = tid; i < NW * NW; i += THREADS)
        sFsub[i] = (f2){Fsub_re[i], Fsub_im[i]};
    if (tid < NS * NS) sFsym[tid] = (f2){Fsym_re[tid], Fsym_im[tid]};

    // ---- chunk0 x: global->reg (latency overlaps F staging), reg->LDS ----
    f2 r0[7];
    STAGE_LOAD(r0, CW0, CH0, 0, MPW * CH0);
    STAGE_WRITE(r0, CW0, CH0, MPW * CH0);
    __syncthreads();   // the ONLY barrier: F tables + own chunk0 drained

    // ---- chunk1 x: issue loads now; latency hides under chunk0 compute ----
    f2 r1[7];
    STAGE_LOAD(r1, CW1, CH1, CW0, MPW * CH1);

    const int g = lane / TPM;                 // 0..4 active, 5 for idle lanes
    const int j = lane - g * TPM;
    const bool act = (lane < MPW * TPM);      // 55 of 64 lanes compute
    const int gg = act ? g : 0;
    const int M = Mw + gg;
    const int Ms = (M < NM) ? M : 0;
    const int n = Ms >> 4, a = Ms & 15;
    const int c0 = 3 * j;

    // ---- Fused A+B, chunk0: V[t][k] += sum_{w<17} x[t][w]*Fsub[w][c0+k] ----
    f2 V[NS][CPT];
#pragma unroll
    for (int t = 0; t < NS; ++t)
#pragma unroll
        for (int k = 0; k < CPT; ++k) V[t][k] = (f2){0.f, 0.f};
    if (act) {
        const f2* bp = wbuf + gg * BUFS;
#pragma unroll 3
        for (int w = 0; w < CW0; ++w) {
            f2 xc[NS];
#pragma unroll
            for (int t = 0; t < NS; ++t) xc[t] = bp[w * NS + t];
            f2 fv[CPT];
#pragma unroll
            for (int k = 0; k < CPT; ++k) fv[k] = sFsub[w * NW + c0 + k];
#pragma unroll
            for (int t = 0; t < NS; ++t)
#pragma unroll
                for (int k = 0; k < CPT; ++k)
                    cmac(V[t][k], xc[t], fv[k]);
        }
    }

    // ---- chunk1 reg->LDS (overwrites chunk0 region; per-wave in-order DS
    //      guarantees the chunk0 ds_reads above sample before these writes) ----
    STAGE_WRITE(r1, CW1, CH1, MPW * CH1);
    asm volatile("s_waitcnt lgkmcnt(0)" ::: "memory");

    // ---- Fused A+B, chunk1: w_global = 17 + w ----
    if (act) {
        const f2* bp = wbuf + gg * BUFS;
#pragma unroll 3
        for (int w = 0; w < CW1; ++w) {
            f2 xc[NS];
#pragma unroll
            for (int t = 0; t < NS; ++t) xc[t] = bp[w * NS + t];
            f2 fv[CPT];
#pragma unroll
            for (int k = 0; k < CPT; ++k) fv[k] = sFsub[(CW0 + w) * NW + c0 + k];
#pragma unroll
            for (int t = 0; t < NS; ++t)
#pragma unroll
                for (int k = 0; k < CPT; ++k)
                    cmac(V[t][k], xc[t], fv[k]);
        }
    }

    // ---- X = F_sym*V; P = |X|^2; Stage D (Hermitian p<3) -> T2 ----
    f2 T2[3][CPT];
#pragma unroll
    for (int p = 0; p < 3; ++p)
#pragma unroll
        for (int k = 0; k < CPT; ++k) T2[p][k] = (f2){0.f, 0.f};
    if (act) {
#pragma unroll
        for (int s = 0; s < NS; ++s) {
            f2 X[CPT];
#pragma unroll
            for (int k = 0; k < CPT; ++k) X[k] = (f2){0.f, 0.f};
#pragma unroll
            for (int t = 0; t < NS; ++t) {
                f2 f = sFsym[s * NS + t];
#pragma unroll
                for (int k = 0; k < CPT; ++k)
                    cmac(X[k], f, V[t][k]);
            }
#pragma unroll
            for (int k = 0; k < CPT; ++k) {
                const float Pv = X[k].x * X[k].x + X[k].y * X[k].y;
                const f2 Pp = (f2){Pv, Pv};
#pragma unroll
                for (int p = 0; p < 3; ++p)
                    cmacr(T2[p][k], sFsym[s * NS + p], Pp);
            }
        }
        // T2 col-major into the same wave-private region (after all x reads).
        f2* const wb = wbuf + gg * BUFS;
#pragma unroll
        for (int k = 0; k < CPT; ++k)
#pragma unroll
            for (int p = 0; p < 3; ++p)
                wb[(c0 + k) * 3 + p] = T2[p][k];
    }
    asm volatile("s_waitcnt lgkmcnt(0)" ::: "memory");

    // ---- Stage E: Y[p][q] = sum_v T2[p][v]*conj(Fsub[q][v]), q = c0+k ----
    if (act) {
        const f2* bp = wbuf + gg * BUFS;
        if (!write_complex) {
            f2 Ypk[3][CPT];
#pragma unroll
            for (int p = 0; p < 3; ++p)
#pragma unroll
                for (int k = 0; k < CPT; ++k) Ypk[p][k] = (f2){0.f, 0.f};
#pragma unroll 3
            for (int v = 0; v < NW; ++v) {
                f2 tc[3];
#pragma unroll
                for (int p = 0; p < 3; ++p) tc[p] = bp[v * 3 + p];
                f2 fw[CPT];
#pragma unroll
                for (int k = 0; k < CPT; ++k) fw[k] = sFsub[(c0 + k) * NW + v];
#pragma unroll
                for (int p = 0; p < 3; ++p)
#pragma unroll
                    for (int k = 0; k < CPT; ++k)
                        pkfma(Ypk[p][k], tc[p], fw[k]);   // Re fold at end
            }
            if (M < NM) {
                int obase = ((n * NS) * NA + a) * NW;
#pragma unroll
                for (int p = 0; p < 3; ++p) {
                    const int pp = (NS - p) % NS;   // 0,4,3
#pragma unroll
                    for (int k = 0; k < CPT; ++k) {
                        const int q = c0 + k;
                        const int qq = (NW - q) % NW;
                        const float Yr = Ypk[p][k].x + Ypk[p][k].y;
                        out[obase + p * (NA * NW) + q] = Yr;
                        out[obase + pp * (NA * NW) + qq] = Yr;
                    }
                }
            }
        } else {
            // Fallback: full complex output (not expected on this harness).
            f2 Y[3][CPT];
#pragma unroll
            for (int p = 0; p < 3; ++p)
#pragma unroll
                for (int k = 0; k < CPT; ++k) Y[p][k] = (f2){0.f, 0.f};
            for (int v = 0; v < NW; ++v) {
                f2 tc[3];
#pragma unroll
                for (int p = 0; p < 3; ++p) tc[p] = bp[v * 3 + p];
                f2 fw[CPT];
#pragma unroll
                for (int k = 0; k < CPT; ++k) fw[k] = sFsub[(c0 + k) * NW + v];
#pragma unroll
                for (int p = 0; p < 3; ++p)
#pragma unroll
                    for (int k = 0; k < CPT; ++k) {
                        Y[p][k].x = fmaf(tc[p].x, fw[k].x, Y[p][k].x);
                        Y[p][k].x = fmaf(tc[p].y, fw[k].y, Y[p][k].x);
                        Y[p][k].y = fmaf(tc[p].y, fw[k].x, Y[p][k].y);
                        Y[p][k].y = fmaf(-tc[p].x, fw[k].y, Y[p][k].y);
                    }
            }
            if (M < NM) {
#pragma unroll
                for (int p = 0; p < 3; ++p) {
                    const int pp = (NS - p) % NS;
#pragma unroll
                    for (int k = 0; k < CPT; ++k) {
                        const int q = c0 + k;
                        const int qq = (NW - q) % NW;
                        ((float2*)out)[((n * NS + p) * NA + a) * NW + q] =
                            make_float2(Y[p][k].x, Y[p][k].y);
                        ((float2*)out)[((n * NS + pp) * NA + a) * NW + qq] =
                            make_float2(Y[p][k].x, -Y[p][k].y);
                    }
                }
            }
        }
    }
}

extern "C" void kernel_launch(void* const* d_in, const int* in_sizes, int n_in,
                              void* d_out, int out_size, void* d_ws, size_t ws_size,
                              hipStream_t stream) {
    const float* x_real  = (const float*)d_in[0];
    const float* x_imag  = (const float*)d_in[1];
    const float* Fsym_re = (const float*)d_in[2];
    const float* Fsym_im = (const float*)d_in[3];
    const float* Fsub_re = (const float*)d_in[4];
    const float* Fsub_im = (const float*)d_in[5];

    const int NM = in_sizes[0] / SW;
    const long long n_cplx = (long long)in_sizes[0];
    const int write_complex = ((long long)out_size >= 2 * n_cplx) ? 1 : 0;

    const int blocks = (NM + GM - 1) / GM;

    autocorr_kernel<<<blocks, THREADS, 0, stream>>>(
        x_real, x_imag, Fsym_re, Fsym_im, Fsub_re, Fsub_im,
        (float*)d_out, NM, write_complex);
}